// Round 8
// baseline (431.961 us; speedup 1.0000x reference)
//
#include <hip/hip_runtime.h>
#include <cstdint>

#define N 8192
#define FIN 256
#define FOUT 128
#define ALPHA 0.2f
#define JP 4                  // j-split (128 row-blocks x 4 = 512 gat blocks)
#define JSL (N / JP)          // 2048 j per block
#define TJ 64                 // j-tile
#define NTILE (JSL / TJ)      // 32 tiles
#define RB 64                 // rows per block (8 waves, 512 threads)
#define SST 72                // S stride in u16 (16B-aligned rows, baseline banks)

typedef unsigned short u16;
typedef unsigned char u8;
typedef __attribute__((ext_vector_type(8))) short short8;
typedef __attribute__((ext_vector_type(4))) float floatx4;

__device__ __forceinline__ u16 bf16_rne(float f) {
  uint32_t u = __float_as_uint(f);
  u += 0x7fff + ((u >> 16) & 1);
  return (u16)(u >> 16);
}

// async global->LDS DMA, 16 B per lane, whole wave. LDS dest = uniform base
// + lane*16 (m104); global src IS per-lane (m173).
__device__ __forceinline__ void gl_lds16(const void* g, void* l) {
  __builtin_amdgcn_global_load_lds(
      (const __attribute__((address_space(1))) void*)g,
      (__attribute__((address_space(3))) void*)l, 16, 0, 0);
}

// ---------------------------------------------------------------------------
// Kernel 1: h = x@W (fp32); hT3 bf16 tiled [jb][nt][m*4+q][8]; src = h@a1,
// dst = h@a2.  (round-2 version, unchanged)
// ---------------------------------------------------------------------------
__global__ __launch_bounds__(256) void k_proj(const float* __restrict__ x,
                                              const float* __restrict__ W,
                                              const float* __restrict__ a,
                                              u16* __restrict__ hT3,
                                              float* __restrict__ srcv,
                                              float* __restrict__ dstv) {
  __shared__ float xs[8 * FIN];                     // 8 KB
  __shared__ float partS[4][4], partD[4][4];
  const int t = threadIdx.x;
  const int R0 = blockIdx.x * 8;

  const float4* xv = (const float4*)(x + (size_t)R0 * FIN);
  float4* xsv = (float4*)xs;
  xsv[t] = xv[t];
  xsv[t + 256] = xv[t + 256];
  __syncthreads();

  const int c  = t & 127;
  const int rg = (t >> 7) * 4;

  float acc[4] = {0.f, 0.f, 0.f, 0.f};
  float wa[4], wb[4];
  #pragma unroll
  for (int j = 0; j < 4; ++j) wa[j] = W[j * FOUT + c];
  #pragma unroll
  for (int j = 0; j < 4; ++j) wb[j] = W[(4 + j) * FOUT + c];

  for (int k4 = 0; k4 < FIN / 4; ++k4) {
    float wc[4];
    #pragma unroll
    for (int j = 0; j < 4; ++j) { wc[j] = wa[j]; wa[j] = wb[j]; }
    const int kn = (k4 + 2 < FIN / 4) ? k4 + 2 : k4;
    #pragma unroll
    for (int j = 0; j < 4; ++j) wb[j] = W[(kn * 4 + j) * FOUT + c];
    #pragma unroll
    for (int i = 0; i < 4; ++i) {
      const float4 xq = *(const float4*)&xs[(rg + i) * FIN + k4 * 4];
      acc[i] += xq.x * wc[0] + xq.y * wc[1] + xq.z * wc[2] + xq.w * wc[3];
    }
  }

  {
    const int j = R0 + rg;
    const int jb = j >> 5, q = (j >> 3) & 3, jj = j & 7;
    const int m = c & 15, nt = c >> 4;
    union { u16 u[4]; uint2 v; } pk;
    #pragma unroll
    for (int i = 0; i < 4; ++i) pk.u[i] = bf16_rne(acc[i]);
    *(uint2*)(hT3 + (size_t)(((jb * 8 + nt) * 64) + (m * 4 + q)) * 8 + jj) = pk.v;
  }

  const float a1 = a[c], a2 = a[FOUT + c];
  float s4[4], d4[4];
  #pragma unroll
  for (int i = 0; i < 4; ++i) { s4[i] = acc[i] * a1; d4[i] = acc[i] * a2; }
  #pragma unroll
  for (int off = 32; off > 0; off >>= 1) {
    #pragma unroll
    for (int i = 0; i < 4; ++i) {
      s4[i] += __shfl_down(s4[i], off);
      d4[i] += __shfl_down(d4[i], off);
    }
  }
  const int wv = t >> 6, lane = t & 63;
  if (lane == 0) {
    #pragma unroll
    for (int i = 0; i < 4; ++i) { partS[wv][i] = s4[i]; partD[wv][i] = d4[i]; }
  }
  __syncthreads();
  if (t < 16) {
    const int i = t & 3, rg2 = (t >> 2) & 1, which = t >> 3;
    if (which == 0) srcv[R0 + rg2 * 4 + i] = partS[rg2*2][i] + partS[rg2*2+1][i];
    else            dstv[R0 + rg2 * 4 + i] = partD[rg2*2][i] + partD[rg2*2+1][i];
  }
}

// ---------------------------------------------------------------------------
// Kernel 2: fused GAT — round-8: RB=64, 512-thread blocks (8 waves).
// r7's flat result showed the staging path is RATE-limited, not
// queue-depth-limited. Per-CU staged bytes are the lever: at RB=32, hT
// amplification = 512 blocks x 1 MB = 512 MB L2->LDS for a 2 MB matrix
// (2/3 of all staged bytes). RB=64 halves it (256 MB): per 32-row unit,
// delivery drops 24 KB -> 16 KB with identical per-wave compute.
// Skeleton = r6 exactly: double-buffer, B1 = vmcnt(2) (retire this tile's
// 4 DMA/wave, keep 2 dst loads in flight), B2 = lgkmcnt(0) only.
// Waves: rh = wv&3 (four 16-row bands), ch = wv>>2 (two 64-col halves).
// LDS 73.2 KB -> 2 blocks/CU (16 waves/CU, same occupancy as r6).
// ---------------------------------------------------------------------------
__global__ __launch_bounds__(512, 4) void k_gat(const int* __restrict__ adj,
                                                const u16* __restrict__ hT3,
                                                const float* __restrict__ srcv,
                                                const float* __restrict__ dstv,
                                                float* __restrict__ P,
                                                float* __restrict__ lp) {
  __shared__ u16 hS[2][8192];      // 2 x 16 KB staged hT tiles
  __shared__ int adjS[2][4096];    // 2 x 16 KB staged adj tiles (64 x 64 int)
  __shared__ u16 S[RB * SST];      // 9.2 KB p-tile (bf16)
  const int t = threadIdx.x;       // 0..511
  const int wv = t >> 6, lane = t & 63;
  const int q = lane >> 4, m = lane & 15;
  const int bm = blockIdx.x & 127;
  const int jp = blockIdx.x >> 7;
  const int R0 = bm * RB;
  const int j0 = jp * JSL;

  // p-phase mapping: thread -> (row pr 0..63, 8 cols at pc)
  const int pr = t >> 3;
  const int pc = (t & 7) * 8;
  const float srcr = srcv[R0 + pr];
  const float* dstp = dstv + j0 + pc;

  // MFMA mapping: wave -> (16-row band rh 0..3, col-half ch 0..1)
  const int rh = wv & 3, ch = wv >> 2;
  const int Lq = m * 4 + q;                      // hT3/hS lane index

  floatx4 acc[4];
  #pragma unroll
  for (int nt = 0; nt < 4; ++nt) acc[nt] = (floatx4){0.f, 0.f, 0.f, 0.f};
  float lsum = 0.f;

  // DMA one tile: hT 16 KB (16 chunks, wave wv: 2) + adj 16 KB (16 chunks,
  // wave wv: 2). adj chunk c_ (1 KB): rows c_*4+(lane>>4), cols (lane&15)*4
  // -> LDS row-major [64][64] int (lane-linear ✓).
  const size_t jb00 = (size_t)(j0 >> 5);         // first global jb of slice
  #define STAGE(I, BUF)                                                        \
  {                                                                            \
    _Pragma("unroll")                                                          \
    for (int cc = 0; cc < 2; ++cc) {                                           \
      const int kc = wv * 2 + cc;               /* 0..15 */                    \
      const int jbl = kc >> 3, nt_ = kc & 7;                                   \
      const u16* src = hT3 + ((jb00 + (size_t)(I) * 2 + jbl) * 8 + nt_) * 512  \
                       + (size_t)lane * 8;                                     \
      gl_lds16(src, &hS[BUF][kc * 512]);                                       \
    }                                                                          \
    _Pragma("unroll")                                                          \
    for (int cc = 0; cc < 2; ++cc) {                                           \
      const int c_ = wv * 2 + cc;               /* 0..15 */                    \
      const int* asrc = adj + (size_t)(R0 + c_ * 4 + (lane >> 4)) * N          \
                        + j0 + (I) * TJ + (lane & 15) * 4;                     \
      gl_lds16(asrc, &adjS[BUF][c_ * 256]);                                    \
    }                                                                          \
  }

  // prologue: stage tile 0 into buf 0; register-prefetch tile-0 dst
  STAGE(0, 0)
  __builtin_amdgcn_sched_barrier(0);   // DMAs strictly oldest in VMEM queue
  float4 dC0 = *(const float4*)(dstp),   dC1 = *(const float4*)(dstp + 4);

  int buf = 0;
  for (int i = 0; i < NTILE; ++i) {
    // B1: retire this tile's 4 DMA chunks (oldest of [S(i):4, dst(i):2]);
    // keep the 2 dst prefetch loads in flight. lgkmcnt(0): all waves' prior
    // LDS reads done before S / hS[buf^1] / adjS[buf^1] get overwritten.
    asm volatile("s_waitcnt vmcnt(2) lgkmcnt(0)" ::: "memory");
    __builtin_amdgcn_s_barrier();
    __builtin_amdgcn_sched_barrier(0);

    // mask for tile i from adjS[buf] (DMA'd last iter, retired at B1);
    // issue the ds_reads before STAGE so their latency hides under it
    const int4 A0 = *((const int4*)adjS[buf] + pr * 16 + (t & 7) * 2);
    const int4 A1 = *((const int4*)adjS[buf] + pr * 16 + (t & 7) * 2 + 1);

    // DMA tile i+1 into the other buffer; reg-prefetch dst for tile i+1
    const int nx = (i + 1 < NTILE) ? i + 1 : i;
    if (i + 1 < NTILE) STAGE(i + 1, buf ^ 1)
    __builtin_amdgcn_sched_barrier(0);   // pin: 4 DMA issued before dst loads
    float4 dN0 = *(const float4*)(dstp + nx * TJ);
    float4 dN1 = *(const float4*)(dstp + nx * TJ + 4);

    // p-phase: 8 p-values/thread (mask from LDS, dst from regs) -> S (bf16)
    {
      const int   ai[8] = {A0.x, A0.y, A0.z, A0.w, A1.x, A1.y, A1.z, A1.w};
      const float df[8] = {dC0.x, dC0.y, dC0.z, dC0.w, dC1.x, dC1.y, dC1.z, dC1.w};
      union { u16 u[8]; short8 s; } pk;
      #pragma unroll
      for (int e = 0; e < 8; ++e) {
        float v = srcr + df[e];
        v = fmaxf(v, ALPHA * v);
        const float p = ai[e] > 0 ? __expf(v) : 0.f;
        lsum += p;
        pk.u[e] = bf16_rne(p);
      }
      *(short8*)&S[pr * SST + pc] = pk.s;
    }

    // B2: LDS-only barrier — S ds_writes visible; DMA for tile i+1 and dst
    // loads remain in flight (no vmcnt drain).
    asm volatile("s_waitcnt lgkmcnt(0)" ::: "memory");
    __builtin_amdgcn_s_barrier();
    __builtin_amdgcn_sched_barrier(0);

    // MFMA: A-frags from S (band rh), B-frags from hS[buf] (half ch)
    {
      const short8 a0 = *(const short8*)&S[(rh * 16 + m) * SST + q * 8];
      const short8 a1 = *(const short8*)&S[(rh * 16 + m) * SST + 32 + q * 8];
      #pragma unroll
      for (int nt = 0; nt < 4; ++nt) {
        const short8 b0 = *(const short8*)&hS[buf][(0 * 8 + ch * 4 + nt) * 512 + Lq * 8];
        const short8 b1 = *(const short8*)&hS[buf][(1 * 8 + ch * 4 + nt) * 512 + Lq * 8];
        acc[nt] = __builtin_amdgcn_mfma_f32_16x16x32_bf16(a0, b0, acc[nt], 0, 0, 0);
        acc[nt] = __builtin_amdgcn_mfma_f32_16x16x32_bf16(a1, b1, acc[nt], 0, 0, 0);
      }
    }

    dC0 = dN0; dC1 = dN1;
    buf ^= 1;
  }
  #undef STAGE

  // row-sum: reduce over the 8 threads sharing row pr (aligned groups)
  lsum += __shfl_down(lsum, 4);
  lsum += __shfl_down(lsum, 2);
  lsum += __shfl_down(lsum, 1);
  if ((t & 7) == 0) lp[(size_t)jp * N + R0 + pr] = lsum;

  // partial store (C/D layout: row = q*4+ri, col = nt*16+m)
  float* Pp = P + ((size_t)jp * N + R0 + rh * 16) * FOUT + ch * 64;
  #pragma unroll
  for (int nt = 0; nt < 4; ++nt)
    #pragma unroll
    for (int ri = 0; ri < 4; ++ri)
      Pp[(size_t)(q * 4 + ri) * FOUT + nt * 16 + m] = acc[nt][ri];
}

// ---------------------------------------------------------------------------
// Kernel 3: sum JP partials, normalize by row-sum. ~36 MB traffic at JP=4.
// ---------------------------------------------------------------------------
__global__ __launch_bounds__(256) void k_norm(const float* __restrict__ P,
                                              const float* __restrict__ lp,
                                              float* __restrict__ out) {
  const int idx = blockIdx.x * 256 + threadIdx.x;   // 0 .. N*FOUT/4-1
  const int rr = idx >> 5;
  const int c4 = (idx & 31) * 4;
  float l = 0.f;
  #pragma unroll
  for (int j = 0; j < JP; ++j) l += lp[j * N + rr];
  const float inv = 1.0f / l;
  float4 s = {0.f, 0.f, 0.f, 0.f};
  #pragma unroll
  for (int j = 0; j < JP; ++j) {
    const float4 p = *(const float4*)(P + ((size_t)j * N + rr) * FOUT + c4);
    s.x += p.x; s.y += p.y; s.z += p.z; s.w += p.w;
  }
  s.x *= inv; s.y *= inv; s.z *= inv; s.w *= inv;
  *(float4*)(out + (size_t)rr * FOUT + c4) = s;
}

extern "C" void kernel_launch(void* const* d_in, const int* in_sizes, int n_in,
                              void* d_out, int out_size, void* d_ws, size_t ws_size,
                              hipStream_t stream) {
  const float* x   = (const float*)d_in[0];
  const int*   adj = (const int*)d_in[1];
  const float* W   = (const float*)d_in[2];
  const float* a   = (const float*)d_in[3];
  float* out = (float*)d_out;

  char* ws = (char*)d_ws;
  u16*   hT3  = (u16*)ws;     ws += (size_t)FOUT * N * sizeof(u16);            // 2 MB
  float* srcv = (float*)ws;   ws += (size_t)N * sizeof(float);
  float* dstv = (float*)ws;   ws += (size_t)N * sizeof(float);
  float* P    = (float*)ws;   ws += (size_t)JP * N * FOUT * sizeof(float);     // 16 MB
  float* lp   = (float*)ws;   ws += (size_t)JP * N * sizeof(float);

  k_proj<<<N / 8, 256, 0, stream>>>(x, W, a, hT3, srcv, dstv);
  k_gat <<<128 * JP, 512, 0, stream>>>(adj, hT3, srcv, dstv, P, lp);
  k_norm<<<(N * FOUT / 4) / 256, 256, 0, stream>>>(P, lp, out);
}

// Round 9
// 414.800 us; speedup vs baseline: 1.0414x; 1.0414x over previous
//
#include <hip/hip_runtime.h>
#include <cstdint>

#define N 8192
#define FIN 256
#define FOUT 128
#define ALPHA 0.2f
#define JP 2                  // j-split (512 gat blocks, 2/CU co-resident)
#define JSL (N / JP)          // 4096 j per block
#define TJ 64                 // j-tile
#define NTILE (JSL / TJ)      // 64 tiles
#define RB 32                 // rows per block
#define SST 72                // S stride in u16 (16B-aligned rows, baseline banks)

typedef unsigned short u16;
typedef unsigned char u8;
typedef __attribute__((ext_vector_type(8))) short short8;
typedef __attribute__((ext_vector_type(4))) float floatx4;

__device__ __forceinline__ u16 bf16_rne(float f) {
  uint32_t u = __float_as_uint(f);
  u += 0x7fff + ((u >> 16) & 1);
  return (u16)(u >> 16);
}

// async global->LDS DMA, 16 B per lane, whole wave. LDS dest = uniform base
// + lane*16 (m104); global src IS per-lane (m173).
__device__ __forceinline__ void gl_lds16(const void* g, void* l) {
  __builtin_amdgcn_global_load_lds(
      (const __attribute__((address_space(1))) void*)g,
      (__attribute__((address_space(3))) void*)l, 16, 0, 0);
}

// NT variant (aux=2 -> CPol NT on gfx94x/950): L2 does not RETAIN the line.
// Used for the single-use 268 MB adj stream so it stops sweeping the 32 MB
// L2 and evicting the 2 MB hT3 that gets re-staged 256x (the r6-r8 merged
// kernels' hidden hT re-fetch from HBM = the additive ~40 us).
__device__ __forceinline__ void gl_lds16_nt(const void* g, void* l) {
  __builtin_amdgcn_global_load_lds(
      (const __attribute__((address_space(1))) void*)g,
      (__attribute__((address_space(3))) void*)l, 16, 0, 2);
}

// ---------------------------------------------------------------------------
// Kernel 1: h = x@W (fp32); hT3 bf16 tiled [jb][nt][m*4+q][8]; src = h@a1,
// dst = h@a2.  (round-2 version, unchanged)
// ---------------------------------------------------------------------------
__global__ __launch_bounds__(256) void k_proj(const float* __restrict__ x,
                                              const float* __restrict__ W,
                                              const float* __restrict__ a,
                                              u16* __restrict__ hT3,
                                              float* __restrict__ srcv,
                                              float* __restrict__ dstv) {
  __shared__ float xs[8 * FIN];                     // 8 KB
  __shared__ float partS[4][4], partD[4][4];
  const int t = threadIdx.x;
  const int R0 = blockIdx.x * 8;

  const float4* xv = (const float4*)(x + (size_t)R0 * FIN);
  float4* xsv = (float4*)xs;
  xsv[t] = xv[t];
  xsv[t + 256] = xv[t + 256];
  __syncthreads();

  const int c  = t & 127;
  const int rg = (t >> 7) * 4;

  float acc[4] = {0.f, 0.f, 0.f, 0.f};
  float wa[4], wb[4];
  #pragma unroll
  for (int j = 0; j < 4; ++j) wa[j] = W[j * FOUT + c];
  #pragma unroll
  for (int j = 0; j < 4; ++j) wb[j] = W[(4 + j) * FOUT + c];

  for (int k4 = 0; k4 < FIN / 4; ++k4) {
    float wc[4];
    #pragma unroll
    for (int j = 0; j < 4; ++j) { wc[j] = wa[j]; wa[j] = wb[j]; }
    const int kn = (k4 + 2 < FIN / 4) ? k4 + 2 : k4;
    #pragma unroll
    for (int j = 0; j < 4; ++j) wb[j] = W[(kn * 4 + j) * FOUT + c];
    #pragma unroll
    for (int i = 0; i < 4; ++i) {
      const float4 xq = *(const float4*)&xs[(rg + i) * FIN + k4 * 4];
      acc[i] += xq.x * wc[0] + xq.y * wc[1] + xq.z * wc[2] + xq.w * wc[3];
    }
  }

  {
    const int j = R0 + rg;
    const int jb = j >> 5, q = (j >> 3) & 3, jj = j & 7;
    const int m = c & 15, nt = c >> 4;
    union { u16 u[4]; uint2 v; } pk;
    #pragma unroll
    for (int i = 0; i < 4; ++i) pk.u[i] = bf16_rne(acc[i]);
    *(uint2*)(hT3 + (size_t)(((jb * 8 + nt) * 64) + (m * 4 + q)) * 8 + jj) = pk.v;
  }

  const float a1 = a[c], a2 = a[FOUT + c];
  float s4[4], d4[4];
  #pragma unroll
  for (int i = 0; i < 4; ++i) { s4[i] = acc[i] * a1; d4[i] = acc[i] * a2; }
  #pragma unroll
  for (int off = 32; off > 0; off >>= 1) {
    #pragma unroll
    for (int i = 0; i < 4; ++i) {
      s4[i] += __shfl_down(s4[i], off);
      d4[i] += __shfl_down(d4[i], off);
    }
  }
  const int wv = t >> 6, lane = t & 63;
  if (lane == 0) {
    #pragma unroll
    for (int i = 0; i < 4; ++i) { partS[wv][i] = s4[i]; partD[wv][i] = d4[i]; }
  }
  __syncthreads();
  if (t < 16) {
    const int i = t & 3, rg2 = (t >> 2) & 1, which = t >> 3;
    if (which == 0) srcv[R0 + rg2 * 4 + i] = partS[rg2*2][i] + partS[rg2*2+1][i];
    else            dstv[R0 + rg2 * 4 + i] = partD[rg2*2][i] + partD[rg2*2+1][i];
  }
}

// ---------------------------------------------------------------------------
// Kernel 2: fused GAT — round-9: EXACT r6 skeleton (best measured config:
// double-buffer, B1 = vmcnt(2), B2 = lgkmcnt(0)-only, JP=2) with ONE change:
// adj DMA uses NT cache policy (gl_lds16_nt). r7 (queue depth) and r8
// (staged bytes / occupancy) were both flat -> the additive ~40 us is not
// scheduling; surviving theory is L2 pollution: the 268 MB adj stream
// sweeps L2 (8 refills/XCD), so the 512 MB of hT re-staging degrades from
// L2-hits to HBM misses (524 MB implied HBM ~ 83 us = measured). NT stops
// adj from being retained in L2; hT (aux=0) stays resident.
// ---------------------------------------------------------------------------
__global__ __launch_bounds__(256, 2) void k_gat(const int* __restrict__ adj,
                                                const u16* __restrict__ hT3,
                                                const float* __restrict__ srcv,
                                                const float* __restrict__ dstv,
                                                float* __restrict__ P,
                                                float* __restrict__ lp) {
  __shared__ u16 hS[2][8192];      // 2 x 16 KB staged hT tiles
  __shared__ int adjS[2][2048];    // 2 x 8 KB staged adj tiles (32 x 64 int)
  __shared__ u16 S[RB * SST];      // 4.6 KB p-tile (bf16)
  const int t = threadIdx.x;
  const int wv = t >> 6, lane = t & 63;
  const int q = lane >> 4, m = lane & 15;
  const int bm = blockIdx.x & 255;
  const int jp = blockIdx.x >> 8;
  const int R0 = bm * RB;
  const int j0 = jp * JSL;

  // p-phase mapping: thread -> (row pr, 8 cols at pc)
  const int pr = t >> 3;
  const int pc = (t & 7) * 8;
  const float srcr = srcv[R0 + pr];
  const float* dstp = dstv + j0 + pc;

  // MFMA mapping: wave -> (row-half rh, col-half ch)
  const int rh = wv & 1, ch = wv >> 1;
  const int Lq = m * 4 + q;                      // hT3/hS lane index

  floatx4 acc[4];
  #pragma unroll
  for (int nt = 0; nt < 4; ++nt) acc[nt] = (floatx4){0.f, 0.f, 0.f, 0.f};
  float lsum = 0.f;

  // DMA one tile: hT 16 KB (16 chunks, wave wv: 4) + adj 8 KB (8 chunks,
  // wave wv: 2, NT). adj chunk c_ (1 KB): rows c_*4+(lane>>4), cols
  // (lane&15)*4 -> LDS row-major [32][64] int (lane-linear ✓).
  const size_t jb00 = (size_t)(j0 >> 5);         // first global jb of slice
  #define STAGE(I, BUF)                                                        \
  {                                                                            \
    _Pragma("unroll")                                                          \
    for (int cc = 0; cc < 4; ++cc) {                                           \
      const int kc = wv * 4 + cc;               /* 0..15 */                    \
      const int jbl = kc >> 3, nt_ = kc & 7;                                   \
      const u16* src = hT3 + ((jb00 + (size_t)(I) * 2 + jbl) * 8 + nt_) * 512  \
                       + (size_t)lane * 8;                                     \
      gl_lds16(src, &hS[BUF][kc * 512]);                                       \
    }                                                                          \
    _Pragma("unroll")                                                          \
    for (int cc = 0; cc < 2; ++cc) {                                           \
      const int c_ = wv * 2 + cc;               /* 0..7 */                     \
      const int* asrc = adj + (size_t)(R0 + c_ * 4 + (lane >> 4)) * N          \
                        + j0 + (I) * TJ + (lane & 15) * 4;                     \
      gl_lds16_nt(asrc, &adjS[BUF][c_ * 256]);                                 \
    }                                                                          \
  }

  // prologue: stage tile 0 into buf 0; register-prefetch tile-0 dst
  STAGE(0, 0)
  __builtin_amdgcn_sched_barrier(0);   // DMAs strictly oldest in VMEM queue
  float4 dC0 = *(const float4*)(dstp),   dC1 = *(const float4*)(dstp + 4);

  int buf = 0;
  for (int i = 0; i < NTILE; ++i) {
    // B1: retire this tile's 6 DMA chunks (oldest); keep the 2 dst prefetch
    // loads in flight. lgkmcnt(0): all waves' prior LDS reads done before
    // S / hS[buf^1] / adjS[buf^1] get overwritten after the barrier.
    asm volatile("s_waitcnt vmcnt(2) lgkmcnt(0)" ::: "memory");
    __builtin_amdgcn_s_barrier();
    __builtin_amdgcn_sched_barrier(0);

    // mask for tile i from adjS[buf] (DMA'd last iter, retired at B1);
    // issue the ds_reads before STAGE so their latency hides under it
    const int4 A0 = *((const int4*)adjS[buf] + pr * 16 + (t & 7) * 2);
    const int4 A1 = *((const int4*)adjS[buf] + pr * 16 + (t & 7) * 2 + 1);

    // DMA tile i+1 into the other buffer; reg-prefetch dst for tile i+1
    const int nx = (i + 1 < NTILE) ? i + 1 : i;
    if (i + 1 < NTILE) STAGE(i + 1, buf ^ 1)
    __builtin_amdgcn_sched_barrier(0);   // pin: 6 DMA issued before dst loads
    float4 dN0 = *(const float4*)(dstp + nx * TJ);
    float4 dN1 = *(const float4*)(dstp + nx * TJ + 4);

    // p-phase: 8 p-values/thread (mask from LDS, dst from regs) -> S (bf16)
    {
      const int   ai[8] = {A0.x, A0.y, A0.z, A0.w, A1.x, A1.y, A1.z, A1.w};
      const float df[8] = {dC0.x, dC0.y, dC0.z, dC0.w, dC1.x, dC1.y, dC1.z, dC1.w};
      union { u16 u[8]; short8 s; } pk;
      #pragma unroll
      for (int e = 0; e < 8; ++e) {
        float v = srcr + df[e];
        v = fmaxf(v, ALPHA * v);
        const float p = ai[e] > 0 ? __expf(v) : 0.f;
        lsum += p;
        pk.u[e] = bf16_rne(p);
      }
      *(short8*)&S[pr * SST + pc] = pk.s;
    }

    // B2: LDS-only barrier — S ds_writes visible; DMA for tile i+1 and dst
    // loads remain in flight (no vmcnt drain).
    asm volatile("s_waitcnt lgkmcnt(0)" ::: "memory");
    __builtin_amdgcn_s_barrier();
    __builtin_amdgcn_sched_barrier(0);

    // MFMA: A-frags from S, B-frags from hS[buf]
    {
      const short8 a0 = *(const short8*)&S[(rh * 16 + m) * SST + q * 8];
      const short8 a1 = *(const short8*)&S[(rh * 16 + m) * SST + 32 + q * 8];
      #pragma unroll
      for (int nt = 0; nt < 4; ++nt) {
        const short8 b0 = *(const short8*)&hS[buf][(0 * 8 + ch * 4 + nt) * 512 + Lq * 8];
        const short8 b1 = *(const short8*)&hS[buf][(1 * 8 + ch * 4 + nt) * 512 + Lq * 8];
        acc[nt] = __builtin_amdgcn_mfma_f32_16x16x32_bf16(a0, b0, acc[nt], 0, 0, 0);
        acc[nt] = __builtin_amdgcn_mfma_f32_16x16x32_bf16(a1, b1, acc[nt], 0, 0, 0);
      }
    }

    dC0 = dN0; dC1 = dN1;
    buf ^= 1;
  }
  #undef STAGE

  // row-sum: reduce over the 8 threads sharing row pr (aligned groups)
  lsum += __shfl_down(lsum, 4);
  lsum += __shfl_down(lsum, 2);
  lsum += __shfl_down(lsum, 1);
  if ((t & 7) == 0) lp[(size_t)jp * N + R0 + pr] = lsum;

  // partial store (C/D layout: row = q*4+ri, col = nt*16+m)
  float* Pp = P + ((size_t)jp * N + R0 + rh * 16) * FOUT + ch * 64;
  #pragma unroll
  for (int nt = 0; nt < 4; ++nt)
    #pragma unroll
    for (int ri = 0; ri < 4; ++ri)
      Pp[(size_t)(q * 4 + ri) * FOUT + nt * 16 + m] = acc[nt][ri];
}

// ---------------------------------------------------------------------------
// Kernel 3: sum JP partials, normalize by row-sum. ~20 MB traffic at JP=2.
// ---------------------------------------------------------------------------
__global__ __launch_bounds__(256) void k_norm(const float* __restrict__ P,
                                              const float* __restrict__ lp,
                                              float* __restrict__ out) {
  const int idx = blockIdx.x * 256 + threadIdx.x;   // 0 .. N*FOUT/4-1
  const int rr = idx >> 5;
  const int c4 = (idx & 31) * 4;
  float l = 0.f;
  #pragma unroll
  for (int j = 0; j < JP; ++j) l += lp[j * N + rr];
  const float inv = 1.0f / l;
  float4 s = {0.f, 0.f, 0.f, 0.f};
  #pragma unroll
  for (int j = 0; j < JP; ++j) {
    const float4 p = *(const float4*)(P + ((size_t)j * N + rr) * FOUT + c4);
    s.x += p.x; s.y += p.y; s.z += p.z; s.w += p.w;
  }
  s.x *= inv; s.y *= inv; s.z *= inv; s.w *= inv;
  *(float4*)(out + (size_t)rr * FOUT + c4) = s;
}

extern "C" void kernel_launch(void* const* d_in, const int* in_sizes, int n_in,
                              void* d_out, int out_size, void* d_ws, size_t ws_size,
                              hipStream_t stream) {
  const float* x   = (const float*)d_in[0];
  const int*   adj = (const int*)d_in[1];
  const float* W   = (const float*)d_in[2];
  const float* a   = (const float*)d_in[3];
  float* out = (float*)d_out;

  char* ws = (char*)d_ws;
  u16*   hT3  = (u16*)ws;     ws += (size_t)FOUT * N * sizeof(u16);            // 2 MB
  float* srcv = (float*)ws;   ws += (size_t)N * sizeof(float);
  float* dstv = (float*)ws;   ws += (size_t)N * sizeof(float);
  float* P    = (float*)ws;   ws += (size_t)JP * N * FOUT * sizeof(float);     // 8 MB
  float* lp   = (float*)ws;   ws += (size_t)JP * N * sizeof(float);

  k_proj<<<N / 8, 256, 0, stream>>>(x, W, a, hT3, srcv, dstv);
  k_gat <<<256 * JP, 256, 0, stream>>>(adj, hT3, srcv, dstv, P, lp);
  k_norm<<<(N * FOUT / 4) / 256, 256, 0, stream>>>(P, lp, out);
}

// Round 10
// 395.898 us; speedup vs baseline: 1.0911x; 1.0477x over previous
//
#include <hip/hip_runtime.h>
#include <cstdint>

#define N 8192
#define FIN 256
#define FOUT 128
#define ALPHA 0.2f
#define JP 4                  // j-split (128 row-blocks x 4 = 512 gat blocks)
#define JSL (N / JP)          // 2048 j per block
#define TJ 64                 // j-tile
#define NTILE (JSL / TJ)      // 32 tiles
#define RB 64                 // rows per block (8 waves, 512 threads)
#define SST 72                // S stride in u16 (16B-aligned rows, baseline banks)

typedef unsigned short u16;
typedef unsigned char u8;
typedef __attribute__((ext_vector_type(8))) short short8;
typedef __attribute__((ext_vector_type(4))) float floatx4;

__device__ __forceinline__ u16 bf16_rne(float f) {
  uint32_t u = __float_as_uint(f);
  u += 0x7fff + ((u >> 16) & 1);
  return (u16)(u >> 16);
}

// async global->LDS DMA, 16 B per lane, whole wave. LDS dest = uniform base
// + lane*16 (m104); global src IS per-lane (m173).
__device__ __forceinline__ void gl_lds16(const void* g, void* l) {
  __builtin_amdgcn_global_load_lds(
      (const __attribute__((address_space(1))) void*)g,
      (__attribute__((address_space(3))) void*)l, 16, 0, 0);
}

// NT variant (aux=2 -> CPol NT): L2 does not RETAIN the line. r9 verified
// -15 us: adj's 268 MB single-use stream was sweeping L2 and evicting the
// hT3 working set (hT re-staging degraded to HBM misses).
__device__ __forceinline__ void gl_lds16_nt(const void* g, void* l) {
  __builtin_amdgcn_global_load_lds(
      (const __attribute__((address_space(1))) void*)g,
      (__attribute__((address_space(3))) void*)l, 16, 0, 2);
}

// ---------------------------------------------------------------------------
// Kernel 1: h = x@W (fp32); hT3 bf16 tiled [jb][nt][m*4+q][8]; src = h@a1,
// dst = h@a2.  (round-2 version, unchanged)
// ---------------------------------------------------------------------------
__global__ __launch_bounds__(256) void k_proj(const float* __restrict__ x,
                                              const float* __restrict__ W,
                                              const float* __restrict__ a,
                                              u16* __restrict__ hT3,
                                              float* __restrict__ srcv,
                                              float* __restrict__ dstv) {
  __shared__ float xs[8 * FIN];                     // 8 KB
  __shared__ float partS[4][4], partD[4][4];
  const int t = threadIdx.x;
  const int R0 = blockIdx.x * 8;

  const float4* xv = (const float4*)(x + (size_t)R0 * FIN);
  float4* xsv = (float4*)xs;
  xsv[t] = xv[t];
  xsv[t + 256] = xv[t + 256];
  __syncthreads();

  const int c  = t & 127;
  const int rg = (t >> 7) * 4;

  float acc[4] = {0.f, 0.f, 0.f, 0.f};
  float wa[4], wb[4];
  #pragma unroll
  for (int j = 0; j < 4; ++j) wa[j] = W[j * FOUT + c];
  #pragma unroll
  for (int j = 0; j < 4; ++j) wb[j] = W[(4 + j) * FOUT + c];

  for (int k4 = 0; k4 < FIN / 4; ++k4) {
    float wc[4];
    #pragma unroll
    for (int j = 0; j < 4; ++j) { wc[j] = wa[j]; wa[j] = wb[j]; }
    const int kn = (k4 + 2 < FIN / 4) ? k4 + 2 : k4;
    #pragma unroll
    for (int j = 0; j < 4; ++j) wb[j] = W[(kn * 4 + j) * FOUT + c];
    #pragma unroll
    for (int i = 0; i < 4; ++i) {
      const float4 xq = *(const float4*)&xs[(rg + i) * FIN + k4 * 4];
      acc[i] += xq.x * wc[0] + xq.y * wc[1] + xq.z * wc[2] + xq.w * wc[3];
    }
  }

  {
    const int j = R0 + rg;
    const int jb = j >> 5, q = (j >> 3) & 3, jj = j & 7;
    const int m = c & 15, nt = c >> 4;
    union { u16 u[4]; uint2 v; } pk;
    #pragma unroll
    for (int i = 0; i < 4; ++i) pk.u[i] = bf16_rne(acc[i]);
    *(uint2*)(hT3 + (size_t)(((jb * 8 + nt) * 64) + (m * 4 + q)) * 8 + jj) = pk.v;
  }

  const float a1 = a[c], a2 = a[FOUT + c];
  float s4[4], d4[4];
  #pragma unroll
  for (int i = 0; i < 4; ++i) { s4[i] = acc[i] * a1; d4[i] = acc[i] * a2; }
  #pragma unroll
  for (int off = 32; off > 0; off >>= 1) {
    #pragma unroll
    for (int i = 0; i < 4; ++i) {
      s4[i] += __shfl_down(s4[i], off);
      d4[i] += __shfl_down(d4[i], off);
    }
  }
  const int wv = t >> 6, lane = t & 63;
  if (lane == 0) {
    #pragma unroll
    for (int i = 0; i < 4; ++i) { partS[wv][i] = s4[i]; partD[wv][i] = d4[i]; }
  }
  __syncthreads();
  if (t < 16) {
    const int i = t & 3, rg2 = (t >> 2) & 1, which = t >> 3;
    if (which == 0) srcv[R0 + rg2 * 4 + i] = partS[rg2*2][i] + partS[rg2*2+1][i];
    else            dstv[R0 + rg2 * 4 + i] = partD[rg2*2][i] + partD[rg2*2+1][i];
  }
}

// ---------------------------------------------------------------------------
// Kernel 2: fused GAT — round-10: r8 structure (RB=64, 512-thread blocks,
// hT staging halved to 256 MB, 16 waves/CU) + r9's NT adj DMA. r8 alone was
// flat because L2 pollution masked the halved hT traffic; r9's NT removed
// the pollution (-15 us). Combo: hT now cache-resident AND half the volume;
// 4 waves/SIMD give better barrier overlap between the 2 co-resident blocks.
// Skeleton: double-buffer, B1 = vmcnt(2) (retire this tile's 4 DMA/wave,
// keep 2 dst loads in flight), B2 = lgkmcnt(0) only. LDS 73.2 KB -> 2/CU.
// ---------------------------------------------------------------------------
__global__ __launch_bounds__(512, 4) void k_gat(const int* __restrict__ adj,
                                                const u16* __restrict__ hT3,
                                                const float* __restrict__ srcv,
                                                const float* __restrict__ dstv,
                                                float* __restrict__ P,
                                                float* __restrict__ lp) {
  __shared__ u16 hS[2][8192];      // 2 x 16 KB staged hT tiles
  __shared__ int adjS[2][4096];    // 2 x 16 KB staged adj tiles (64 x 64 int)
  __shared__ u16 S[RB * SST];      // 9.2 KB p-tile (bf16)
  const int t = threadIdx.x;       // 0..511
  const int wv = t >> 6, lane = t & 63;
  const int q = lane >> 4, m = lane & 15;
  const int bm = blockIdx.x & 127;
  const int jp = blockIdx.x >> 7;
  const int R0 = bm * RB;
  const int j0 = jp * JSL;

  // p-phase mapping: thread -> (row pr 0..63, 8 cols at pc)
  const int pr = t >> 3;
  const int pc = (t & 7) * 8;
  const float srcr = srcv[R0 + pr];
  const float* dstp = dstv + j0 + pc;

  // MFMA mapping: wave -> (16-row band rh 0..3, col-half ch 0..1)
  const int rh = wv & 3, ch = wv >> 2;
  const int Lq = m * 4 + q;                      // hT3/hS lane index

  floatx4 acc[4];
  #pragma unroll
  for (int nt = 0; nt < 4; ++nt) acc[nt] = (floatx4){0.f, 0.f, 0.f, 0.f};
  float lsum = 0.f;

  // DMA one tile: hT 16 KB (16 chunks, wave wv: 2) + adj 16 KB (16 chunks,
  // wave wv: 2, NT). adj chunk c_ (1 KB): rows c_*4+(lane>>4), cols
  // (lane&15)*4 -> LDS row-major [64][64] int (lane-linear ✓).
  const size_t jb00 = (size_t)(j0 >> 5);         // first global jb of slice
  #define STAGE(I, BUF)                                                        \
  {                                                                            \
    _Pragma("unroll")                                                          \
    for (int cc = 0; cc < 2; ++cc) {                                           \
      const int kc = wv * 2 + cc;               /* 0..15 */                    \
      const int jbl = kc >> 3, nt_ = kc & 7;                                   \
      const u16* src = hT3 + ((jb00 + (size_t)(I) * 2 + jbl) * 8 + nt_) * 512  \
                       + (size_t)lane * 8;                                     \
      gl_lds16(src, &hS[BUF][kc * 512]);                                       \
    }                                                                          \
    _Pragma("unroll")                                                          \
    for (int cc = 0; cc < 2; ++cc) {                                           \
      const int c_ = wv * 2 + cc;               /* 0..15 */                    \
      const int* asrc = adj + (size_t)(R0 + c_ * 4 + (lane >> 4)) * N          \
                        + j0 + (I) * TJ + (lane & 15) * 4;                     \
      gl_lds16_nt(asrc, &adjS[BUF][c_ * 256]);                                 \
    }                                                                          \
  }

  // prologue: stage tile 0 into buf 0; register-prefetch tile-0 dst
  STAGE(0, 0)
  __builtin_amdgcn_sched_barrier(0);   // DMAs strictly oldest in VMEM queue
  float4 dC0 = *(const float4*)(dstp),   dC1 = *(const float4*)(dstp + 4);

  int buf = 0;
  for (int i = 0; i < NTILE; ++i) {
    // B1: retire this tile's 4 DMA chunks (oldest of [S(i):4, dst(i):2]);
    // keep the 2 dst prefetch loads in flight. lgkmcnt(0): all waves' prior
    // LDS reads done before S / hS[buf^1] / adjS[buf^1] get overwritten.
    asm volatile("s_waitcnt vmcnt(2) lgkmcnt(0)" ::: "memory");
    __builtin_amdgcn_s_barrier();
    __builtin_amdgcn_sched_barrier(0);

    // mask for tile i from adjS[buf] (DMA'd last iter, retired at B1);
    // issue the ds_reads before STAGE so their latency hides under it
    const int4 A0 = *((const int4*)adjS[buf] + pr * 16 + (t & 7) * 2);
    const int4 A1 = *((const int4*)adjS[buf] + pr * 16 + (t & 7) * 2 + 1);

    // DMA tile i+1 into the other buffer; reg-prefetch dst for tile i+1
    const int nx = (i + 1 < NTILE) ? i + 1 : i;
    if (i + 1 < NTILE) STAGE(i + 1, buf ^ 1)
    __builtin_amdgcn_sched_barrier(0);   // pin: 4 DMA issued before dst loads
    float4 dN0 = *(const float4*)(dstp + nx * TJ);
    float4 dN1 = *(const float4*)(dstp + nx * TJ + 4);

    // p-phase: 8 p-values/thread (mask from LDS, dst from regs) -> S (bf16)
    {
      const int   ai[8] = {A0.x, A0.y, A0.z, A0.w, A1.x, A1.y, A1.z, A1.w};
      const float df[8] = {dC0.x, dC0.y, dC0.z, dC0.w, dC1.x, dC1.y, dC1.z, dC1.w};
      union { u16 u[8]; short8 s; } pk;
      #pragma unroll
      for (int e = 0; e < 8; ++e) {
        float v = srcr + df[e];
        v = fmaxf(v, ALPHA * v);
        const float p = ai[e] > 0 ? __expf(v) : 0.f;
        lsum += p;
        pk.u[e] = bf16_rne(p);
      }
      *(short8*)&S[pr * SST + pc] = pk.s;
    }

    // B2: LDS-only barrier — S ds_writes visible; DMA for tile i+1 and dst
    // loads remain in flight (no vmcnt drain).
    asm volatile("s_waitcnt lgkmcnt(0)" ::: "memory");
    __builtin_amdgcn_s_barrier();
    __builtin_amdgcn_sched_barrier(0);

    // MFMA: A-frags from S (band rh), B-frags from hS[buf] (half ch)
    {
      const short8 a0 = *(const short8*)&S[(rh * 16 + m) * SST + q * 8];
      const short8 a1 = *(const short8*)&S[(rh * 16 + m) * SST + 32 + q * 8];
      #pragma unroll
      for (int nt = 0; nt < 4; ++nt) {
        const short8 b0 = *(const short8*)&hS[buf][(0 * 8 + ch * 4 + nt) * 512 + Lq * 8];
        const short8 b1 = *(const short8*)&hS[buf][(1 * 8 + ch * 4 + nt) * 512 + Lq * 8];
        acc[nt] = __builtin_amdgcn_mfma_f32_16x16x32_bf16(a0, b0, acc[nt], 0, 0, 0);
        acc[nt] = __builtin_amdgcn_mfma_f32_16x16x32_bf16(a1, b1, acc[nt], 0, 0, 0);
      }
    }

    dC0 = dN0; dC1 = dN1;
    buf ^= 1;
  }
  #undef STAGE

  // row-sum: reduce over the 8 threads sharing row pr (aligned groups)
  lsum += __shfl_down(lsum, 4);
  lsum += __shfl_down(lsum, 2);
  lsum += __shfl_down(lsum, 1);
  if ((t & 7) == 0) lp[(size_t)jp * N + R0 + pr] = lsum;

  // partial store (C/D layout: row = q*4+ri, col = nt*16+m)
  float* Pp = P + ((size_t)jp * N + R0 + rh * 16) * FOUT + ch * 64;
  #pragma unroll
  for (int nt = 0; nt < 4; ++nt)
    #pragma unroll
    for (int ri = 0; ri < 4; ++ri)
      Pp[(size_t)(q * 4 + ri) * FOUT + nt * 16 + m] = acc[nt][ri];
}

// ---------------------------------------------------------------------------
// Kernel 3: sum JP partials, normalize by row-sum. ~36 MB traffic at JP=4.
// ---------------------------------------------------------------------------
__global__ __launch_bounds__(256) void k_norm(const float* __restrict__ P,
                                              const float* __restrict__ lp,
                                              float* __restrict__ out) {
  const int idx = blockIdx.x * 256 + threadIdx.x;   // 0 .. N*FOUT/4-1
  const int rr = idx >> 5;
  const int c4 = (idx & 31) * 4;
  float l = 0.f;
  #pragma unroll
  for (int j = 0; j < JP; ++j) l += lp[j * N + rr];
  const float inv = 1.0f / l;
  float4 s = {0.f, 0.f, 0.f, 0.f};
  #pragma unroll
  for (int j = 0; j < JP; ++j) {
    const float4 p = *(const float4*)(P + ((size_t)j * N + rr) * FOUT + c4);
    s.x += p.x; s.y += p.y; s.z += p.z; s.w += p.w;
  }
  s.x *= inv; s.y *= inv; s.z *= inv; s.w *= inv;
  *(float4*)(out + (size_t)rr * FOUT + c4) = s;
}

extern "C" void kernel_launch(void* const* d_in, const int* in_sizes, int n_in,
                              void* d_out, int out_size, void* d_ws, size_t ws_size,
                              hipStream_t stream) {
  const float* x   = (const float*)d_in[0];
  const int*   adj = (const int*)d_in[1];
  const float* W   = (const float*)d_in[2];
  const float* a   = (const float*)d_in[3];
  float* out = (float*)d_out;

  char* ws = (char*)d_ws;
  u16*   hT3  = (u16*)ws;     ws += (size_t)FOUT * N * sizeof(u16);            // 2 MB
  float* srcv = (float*)ws;   ws += (size_t)N * sizeof(float);
  float* dstv = (float*)ws;   ws += (size_t)N * sizeof(float);
  float* P    = (float*)ws;   ws += (size_t)JP * N * FOUT * sizeof(float);     // 16 MB
  float* lp   = (float*)ws;   ws += (size_t)JP * N * sizeof(float);

  k_proj<<<N / 8, 256, 0, stream>>>(x, W, a, hT3, srcv, dstv);
  k_gat <<<128 * JP, 512, 0, stream>>>(adj, hT3, srcv, dstv, P, lp);
  k_norm<<<(N * FOUT / 4) / 256, 256, 0, stream>>>(P, lp, out);
}